// Round 2
// baseline (3143.333 us; speedup 1.0000x reference)
//
#include <hip/hip_runtime.h>
#include <cstdint>
#include <cstddef>

#define T_SEQ 2048
#define DM    1024
#define HK    256
#define HV    512
#define NH    4
#define KDIM  1024
#define VDIM  2048

// ---------------- GEMM: C[M,N] = A[M,K] @ W[N,K]^T (both row-major) ----------
__global__ __launch_bounds__(256) void gemm_f32(const float* __restrict__ A,
                                                const float* __restrict__ W,
                                                float* __restrict__ C,
                                                int M, int N, int K) {
  __shared__ float As[16][132];
  __shared__ float Ws[16][132];
  const int t  = threadIdx.x;
  const int bm = blockIdx.y * 128;
  const int bn = blockIdx.x * 128;
  const int m0 = (t >> 4) * 8;
  const int n0 = (t & 15) * 8;
  float acc[8][8];
#pragma unroll
  for (int i = 0; i < 8; ++i)
#pragma unroll
    for (int j = 0; j < 8; ++j) acc[i][j] = 0.f;

  for (int k0 = 0; k0 < K; k0 += 16) {
    float4 av[2], wv[2];
#pragma unroll
    for (int r = 0; r < 2; ++r) {
      int id  = t + 256 * r;
      int row = id >> 2;
      int kc  = (id & 3) << 2;
      av[r] = *(const float4*)(A + (size_t)(bm + row) * K + k0 + kc);
      wv[r] = *(const float4*)(W + (size_t)(bn + row) * K + k0 + kc);
    }
    __syncthreads();
#pragma unroll
    for (int r = 0; r < 2; ++r) {
      int id  = t + 256 * r;
      int row = id >> 2;
      int kc  = (id & 3) << 2;
      As[kc + 0][row] = av[r].x; As[kc + 1][row] = av[r].y;
      As[kc + 2][row] = av[r].z; As[kc + 3][row] = av[r].w;
      Ws[kc + 0][row] = wv[r].x; Ws[kc + 1][row] = wv[r].y;
      Ws[kc + 2][row] = wv[r].z; Ws[kc + 3][row] = wv[r].w;
    }
    __syncthreads();
#pragma unroll
    for (int kk = 0; kk < 16; ++kk) {
      float am[8], wn[8];
      *(float4*)&am[0] = *(const float4*)&As[kk][m0];
      *(float4*)&am[4] = *(const float4*)&As[kk][m0 + 4];
      *(float4*)&wn[0] = *(const float4*)&Ws[kk][n0];
      *(float4*)&wn[4] = *(const float4*)&Ws[kk][n0 + 4];
#pragma unroll
      for (int i = 0; i < 8; ++i)
#pragma unroll
        for (int j = 0; j < 8; ++j)
          acc[i][j] = fmaf(am[i], wn[j], acc[i][j]);
    }
  }
#pragma unroll
  for (int i = 0; i < 8; ++i) {
    float4 c0 = make_float4(acc[i][0], acc[i][1], acc[i][2], acc[i][3]);
    float4 c1 = make_float4(acc[i][4], acc[i][5], acc[i][6], acc[i][7]);
    *(float4*)(C + (size_t)(bm + m0 + i) * N + bn + n0)     = c0;
    *(float4*)(C + (size_t)(bm + m0 + i) * N + bn + n0 + 4) = c1;
  }
}

// ---------------- RoPE (in-place on q and k), q also scaled by HK^-0.5 -------
__global__ __launch_bounds__(256) void rope_kernel(float* __restrict__ q,
                                                   float* __restrict__ k) {
  int idx = blockIdx.x * 256 + threadIdx.x;     // over B*T*H*128 = 4,194,304
  int f  = idx & 127;
  int h  = (idx >> 7) & 3;
  int tt = (idx >> 9) & 2047;
  int b  = idx >> 20;
  size_t a0 = ((size_t)(b * T_SEQ + tt)) * KDIM + h * HK + f;
  size_t a1 = a0 + 128;
  float invf = powf(10000.0f, -(float)f * (1.0f / 128.0f));
  float ang  = (float)tt * invf;
  float s, c;
  sincosf(ang, &s, &c);
  float q1 = q[a0], q2 = q[a1];
  q[a0] = (q1 * c - q2 * s) * 0.0625f;
  q[a1] = (q2 * c + q1 * s) * 0.0625f;
  float k1 = k[a0], k2 = k[a1];
  k[a0] = k1 * c - k2 * s;
  k[a1] = k2 * c + k1 * s;
}

// ---------------- Retention pass 1: intra-chunk (fully parallel) -------------
// one WG per (chunk n, head h, batch b); writes o = attn@v (masked/decayed)
__global__ __launch_bounds__(256) void retn_intra(const float* __restrict__ q,
                                                  const float* __restrict__ k,
                                                  const float* __restrict__ v,
                                                  float* __restrict__ o) {
  const int n = blockIdx.x, h = blockIdx.y, b = blockIdx.z;
  const int t = threadIdx.x;
  const int t0 = n * 64;
  __shared__ float gpow[65];
  __shared__ float qS[64][65];
  __shared__ float kS[64][65];
  __shared__ float attnS[64][65];
  if (t <= 64) {
    float gamma = 1.0f - exp2f(-5.0f - (float)h);
    gpow[t] = powf(gamma, (float)t);
  }
  const size_t baseQK = (size_t)(b * T_SEQ + t0) * KDIM + h * HK;
  const size_t baseV  = (size_t)(b * T_SEQ + t0) * VDIM + h * HV;
  const int i0 = (t >> 4) * 4;
  const int j0 = (t & 15) * 4;
  float acc[4][4] = {};
  for (int s = 0; s < 4; ++s) {              // dk slices of 64
    __syncthreads();
#pragma unroll
    for (int r = 0; r < 16; ++r) {
      int idx = t + 256 * r;
      int row = idx >> 6, col = idx & 63;
      qS[row][col] = q[baseQK + (size_t)row * KDIM + s * 64 + col];
      kS[row][col] = k[baseQK + (size_t)row * KDIM + s * 64 + col];
    }
    __syncthreads();
    for (int d = 0; d < 64; ++d) {
      float a0 = qS[i0][d], a1 = qS[i0 + 1][d], a2 = qS[i0 + 2][d], a3 = qS[i0 + 3][d];
#pragma unroll
      for (int jj = 0; jj < 4; ++jj) {
        float bv = kS[j0 + jj][d];
        acc[0][jj] = fmaf(a0, bv, acc[0][jj]);
        acc[1][jj] = fmaf(a1, bv, acc[1][jj]);
        acc[2][jj] = fmaf(a2, bv, acc[2][jj]);
        acc[3][jj] = fmaf(a3, bv, acc[3][jj]);
      }
    }
  }
  __syncthreads();
#pragma unroll
  for (int ii = 0; ii < 4; ++ii)
#pragma unroll
    for (int jj = 0; jj < 4; ++jj) {
      int i = i0 + ii, j = j0 + jj;
      attnS[i][j] = (i >= j) ? acc[ii][jj] * gpow[i - j] : 0.0f;
    }
  // o_intra = attn @ v  (512 cols in 8 blocks of 64), vS aliases qS
  float (*vS)[65] = qS;
  for (int vb = 0; vb < 8; ++vb) {
    __syncthreads();
#pragma unroll
    for (int r = 0; r < 16; ++r) {
      int idx = t + 256 * r;
      int row = idx >> 6, col = idx & 63;
      vS[row][col] = v[baseV + (size_t)row * VDIM + vb * 64 + col];
    }
    __syncthreads();
    float oa[4][4] = {};
    for (int j = 0; j < 64; ++j) {
      float a0 = attnS[i0][j], a1 = attnS[i0 + 1][j], a2 = attnS[i0 + 2][j], a3 = attnS[i0 + 3][j];
#pragma unroll
      for (int jj = 0; jj < 4; ++jj) {
        float bv = vS[j][j0 + jj];
        oa[0][jj] = fmaf(a0, bv, oa[0][jj]);
        oa[1][jj] = fmaf(a1, bv, oa[1][jj]);
        oa[2][jj] = fmaf(a2, bv, oa[2][jj]);
        oa[3][jj] = fmaf(a3, bv, oa[3][jj]);
      }
    }
#pragma unroll
    for (int ii = 0; ii < 4; ++ii)
#pragma unroll
      for (int jj = 0; jj < 4; ++jj)
        o[baseV + (size_t)(i0 + ii) * VDIM + vb * 64 + j0 + jj] = oa[ii][jj];
  }
}

// ---------------- Retention pass 2: sequential inter-chunk state scan --------
// one WG per (dv-tile of 64, head, batch) = 128 WGs. Thread t owns state row
// dk=t (64 f32 in registers). Per chunk: o += (q*cross_dec)@S ; S = gC*S + (kdec*K)^T@V
__global__ __launch_bounds__(256) void retn_inter(const float* __restrict__ q,
                                                  const float* __restrict__ k,
                                                  const float* __restrict__ v,
                                                  float* __restrict__ o) {
  const int vt = blockIdx.x, h = blockIdx.y, b = blockIdx.z;
  const int t = threadIdx.x;
  __shared__ float gpow[65];
  __shared__ float vS[64][65];
  __shared__ float sS[64][65];
  __shared__ float qS[64][65];
  if (t <= 64) {
    float gamma = 1.0f - exp2f(-5.0f - (float)h);
    gpow[t] = powf(gamma, (float)t);
  }
  __syncthreads();
  const float gC = gpow[64];
  const size_t baseQ = (size_t)(b * T_SEQ) * KDIM + h * HK;
  const size_t baseV = (size_t)(b * T_SEQ) * VDIM + h * HV + vt * 64;
  const int i0 = (t >> 4) * 4;
  const int v0 = (t & 15) * 4;
  float S[64];
#pragma unroll
  for (int c = 0; c < 64; ++c) S[c] = 0.f;

  for (int n = 0; n < 32; ++n) {
    const int t0 = n * 64;
    __syncthreads();   // protect vS/qS/sS from previous iteration's readers
    // stage V slice (64 rows x 64 dv cols)
#pragma unroll
    for (int r = 0; r < 16; ++r) {
      int idx = t + 256 * r;
      int row = idx >> 6, col = idx & 63;
      vS[row][col] = v[baseV + (size_t)(t0 + row) * VDIM + col];
    }
    // o_inter = (q * cross_dec) @ S, over 4 dk-slices of 64
    float oa[4][4] = {};
    for (int s = 0; s < 4; ++s) {
      __syncthreads();
      if ((t >> 6) == s) {                 // wave s publishes its S rows
        int d = t & 63;
#pragma unroll
        for (int c = 0; c < 64; ++c) sS[d][c] = S[c];
      }
      // stage q slice: 64 rows x 64 dk-cols  (FIXED: r<16, was r<4 -> 3/4 of
      // the tile was stale LDS, corrupting the whole o_inter term)
#pragma unroll
      for (int r = 0; r < 16; ++r) {
        int idx = t + 256 * r;
        int row = idx >> 6, col = idx & 63;
        qS[row][col] = q[baseQ + (size_t)(t0 + row) * KDIM + s * 64 + col] * gpow[row + 1];
      }
      __syncthreads();
      for (int d = 0; d < 64; ++d) {
        float a0 = qS[i0][d], a1 = qS[i0 + 1][d], a2 = qS[i0 + 2][d], a3 = qS[i0 + 3][d];
#pragma unroll
        for (int jj = 0; jj < 4; ++jj) {
          float sv = sS[d][v0 + jj];
          oa[0][jj] = fmaf(a0, sv, oa[0][jj]);
          oa[1][jj] = fmaf(a1, sv, oa[1][jj]);
          oa[2][jj] = fmaf(a2, sv, oa[2][jj]);
          oa[3][jj] = fmaf(a3, sv, oa[3][jj]);
        }
      }
    }
    // accumulate into o (on top of o_intra from pass 1)
#pragma unroll
    for (int ii = 0; ii < 4; ++ii) {
      size_t addr = baseV + (size_t)(t0 + i0 + ii) * VDIM + v0;
#pragma unroll
      for (int jj = 0; jj < 4; ++jj) o[addr + jj] += oa[ii][jj];
    }
    // state update: S = gC*S + sum_j kdec[j]*K[j][dk=t]*V[j][:]
#pragma unroll
    for (int c = 0; c < 64; ++c) S[c] *= gC;
    for (int j = 0; j < 64; ++j) {
      float kval = k[baseQ + (size_t)(t0 + j) * KDIM + t] * gpow[63 - j];
#pragma unroll
      for (int c = 0; c < 64; ++c) S[c] = fmaf(kval, vS[j][c], S[c]);
    }
  }
}

// ---------------- RMS group-norm over HEAD_V + SiLU(g) gate (in-place) -------
__global__ __launch_bounds__(256) void norm_gate(float* __restrict__ o,
                                                 const float* __restrict__ g,
                                                 const float* __restrict__ gnw) {
  const int row = blockIdx.x;                 // (b*T + t)*H + h, 32768 rows
  const size_t base = (size_t)row * 512;
  const int t = threadIdx.x;
  float x0 = o[base + t], x1 = o[base + t + 256];
  float ss = x0 * x0 + x1 * x1;
#pragma unroll
  for (int off = 32; off > 0; off >>= 1) ss += __shfl_down(ss, off, 64);
  __shared__ float wsum[4];
  if ((t & 63) == 0) wsum[t >> 6] = ss;
  __syncthreads();
  float tot = wsum[0] + wsum[1] + wsum[2] + wsum[3];
  float scale = rsqrtf(tot * (1.0f / 512.0f) + 1e-5f);
  float g0 = g[base + t], g1 = g[base + t + 256];
  o[base + t]       = x0 * scale * gnw[t]       * (g0 / (1.0f + expf(-g0)));
  o[base + t + 256] = x1 * scale * gnw[t + 256] * (g1 / (1.0f + expf(-g1)));
}

extern "C" void kernel_launch(void* const* d_in, const int* in_sizes, int n_in,
                              void* d_out, int out_size, void* d_ws, size_t ws_size,
                              hipStream_t stream) {
  const float* x   = (const float*)d_in[0];
  const float* Wq  = (const float*)d_in[1];
  const float* Wk  = (const float*)d_in[2];
  const float* Wv  = (const float*)d_in[3];
  const float* Wg  = (const float*)d_in[4];
  const float* Wo  = (const float*)d_in[5];
  const float* gnw = (const float*)d_in[6];
  float* out = (float*)d_out;

  // workspace layout (192 MiB total):
  //   [q: 32MiB][k: 32MiB][v: 64MiB][o: 64MiB]; g reuses the q+k region
  //   (g is only needed after retention, when q,k are dead)
  float* q  = (float*)d_ws;                       //  8192*1024
  float* kk = q  + (size_t)8192 * 1024;           //  8192*1024
  float* v  = kk + (size_t)8192 * 1024;           //  8192*2048
  float* o  = v  + (size_t)8192 * 2048;           //  8192*2048
  float* g  = q;                                  //  8192*2048 (aliases q,k)

  dim3 blk(256);
  gemm_f32<<<dim3(8, 64),  blk, 0, stream>>>(x, Wq, q,  8192, 1024, 1024);
  gemm_f32<<<dim3(8, 64),  blk, 0, stream>>>(x, Wk, kk, 8192, 1024, 1024);
  gemm_f32<<<dim3(16, 64), blk, 0, stream>>>(x, Wv, v,  8192, 2048, 1024);
  rope_kernel<<<dim3(16384), blk, 0, stream>>>(q, kk);
  retn_intra<<<dim3(32, 4, 4), blk, 0, stream>>>(q, kk, v, o);
  retn_inter<<<dim3(8, 4, 4),  blk, 0, stream>>>(q, kk, v, o);
  gemm_f32<<<dim3(16, 64), blk, 0, stream>>>(x, Wg, g,  8192, 2048, 1024);
  norm_gate<<<dim3(32768), blk, 0, stream>>>(o, g, gnw);
  gemm_f32<<<dim3(8, 64),  blk, 0, stream>>>(o, Wo, out, 8192, 1024, 2048);
}

// Round 3
// 2842.385 us; speedup vs baseline: 1.1059x; 1.1059x over previous
//
#include <hip/hip_runtime.h>
#include <cstdint>
#include <cstddef>

#define T_SEQ 2048
#define DM    1024
#define HK    256
#define HV    512
#define NH    4
#define KDIM  1024
#define VDIM  2048

// ---------------- GEMM: C[M,N] = A[M,K] @ W[N,K]^T (both row-major) ----------
__global__ __launch_bounds__(256) void gemm_f32(const float* __restrict__ A,
                                                const float* __restrict__ W,
                                                float* __restrict__ C,
                                                int M, int N, int K) {
  __shared__ float As[16][132];
  __shared__ float Ws[16][132];
  const int t  = threadIdx.x;
  const int bm = blockIdx.y * 128;
  const int bn = blockIdx.x * 128;
  const int m0 = (t >> 4) * 8;
  const int n0 = (t & 15) * 8;
  float acc[8][8];
#pragma unroll
  for (int i = 0; i < 8; ++i)
#pragma unroll
    for (int j = 0; j < 8; ++j) acc[i][j] = 0.f;

  for (int k0 = 0; k0 < K; k0 += 16) {
    float4 av[2], wv[2];
#pragma unroll
    for (int r = 0; r < 2; ++r) {
      int id  = t + 256 * r;
      int row = id >> 2;
      int kc  = (id & 3) << 2;
      av[r] = *(const float4*)(A + (size_t)(bm + row) * K + k0 + kc);
      wv[r] = *(const float4*)(W + (size_t)(bn + row) * K + k0 + kc);
    }
    __syncthreads();
#pragma unroll
    for (int r = 0; r < 2; ++r) {
      int id  = t + 256 * r;
      int row = id >> 2;
      int kc  = (id & 3) << 2;
      As[kc + 0][row] = av[r].x; As[kc + 1][row] = av[r].y;
      As[kc + 2][row] = av[r].z; As[kc + 3][row] = av[r].w;
      Ws[kc + 0][row] = wv[r].x; Ws[kc + 1][row] = wv[r].y;
      Ws[kc + 2][row] = wv[r].z; Ws[kc + 3][row] = wv[r].w;
    }
    __syncthreads();
#pragma unroll
    for (int kk = 0; kk < 16; ++kk) {
      float am[8], wn[8];
      *(float4*)&am[0] = *(const float4*)&As[kk][m0];
      *(float4*)&am[4] = *(const float4*)&As[kk][m0 + 4];
      *(float4*)&wn[0] = *(const float4*)&Ws[kk][n0];
      *(float4*)&wn[4] = *(const float4*)&Ws[kk][n0 + 4];
#pragma unroll
      for (int i = 0; i < 8; ++i)
#pragma unroll
        for (int j = 0; j < 8; ++j)
          acc[i][j] = fmaf(am[i], wn[j], acc[i][j]);
    }
  }
#pragma unroll
  for (int i = 0; i < 8; ++i) {
    float4 c0 = make_float4(acc[i][0], acc[i][1], acc[i][2], acc[i][3]);
    float4 c1 = make_float4(acc[i][4], acc[i][5], acc[i][6], acc[i][7]);
    *(float4*)(C + (size_t)(bm + m0 + i) * N + bn + n0)     = c0;
    *(float4*)(C + (size_t)(bm + m0 + i) * N + bn + n0 + 4) = c1;
  }
}

// ---------------- RoPE (in-place on q and k), q also scaled by HK^-0.5 -------
__global__ __launch_bounds__(256) void rope_kernel(float* __restrict__ q,
                                                   float* __restrict__ k) {
  int idx = blockIdx.x * 256 + threadIdx.x;     // over B*T*H*128 = 4,194,304
  int f  = idx & 127;
  int h  = (idx >> 7) & 3;
  int tt = (idx >> 9) & 2047;
  int b  = idx >> 20;
  size_t a0 = ((size_t)(b * T_SEQ + tt)) * KDIM + h * HK + f;
  size_t a1 = a0 + 128;
  float invf = powf(10000.0f, -(float)f * (1.0f / 128.0f));
  float ang  = (float)tt * invf;
  float s, c;
  sincosf(ang, &s, &c);
  float q1 = q[a0], q2 = q[a1];
  q[a0] = (q1 * c - q2 * s) * 0.0625f;
  q[a1] = (q2 * c + q1 * s) * 0.0625f;
  float k1 = k[a0], k2 = k[a1];
  k[a0] = k1 * c - k2 * s;
  k[a1] = k2 * c + k1 * s;
}

// ---------------- Retention pass 1: intra-chunk (fully parallel) -------------
__global__ __launch_bounds__(256) void retn_intra(const float* __restrict__ q,
                                                  const float* __restrict__ k,
                                                  const float* __restrict__ v,
                                                  float* __restrict__ o) {
  const int n = blockIdx.x, h = blockIdx.y, b = blockIdx.z;
  const int t = threadIdx.x;
  const int t0 = n * 64;
  __shared__ float gpow[65];
  __shared__ float qS[64][65];
  __shared__ float kS[64][65];
  __shared__ float attnS[64][65];
  if (t <= 64) {
    float gamma = 1.0f - exp2f(-5.0f - (float)h);
    gpow[t] = powf(gamma, (float)t);
  }
  const size_t baseQK = (size_t)(b * T_SEQ + t0) * KDIM + h * HK;
  const size_t baseV  = (size_t)(b * T_SEQ + t0) * VDIM + h * HV;
  const int i0 = (t >> 4) * 4;
  const int j0 = (t & 15) * 4;
  float acc[4][4] = {};
  for (int s = 0; s < 4; ++s) {              // dk slices of 64
    __syncthreads();
#pragma unroll
    for (int r = 0; r < 16; ++r) {
      int idx = t + 256 * r;
      int row = idx >> 6, col = idx & 63;
      qS[row][col] = q[baseQK + (size_t)row * KDIM + s * 64 + col];
      kS[row][col] = k[baseQK + (size_t)row * KDIM + s * 64 + col];
    }
    __syncthreads();
    for (int d = 0; d < 64; ++d) {
      float a0 = qS[i0][d], a1 = qS[i0 + 1][d], a2 = qS[i0 + 2][d], a3 = qS[i0 + 3][d];
#pragma unroll
      for (int jj = 0; jj < 4; ++jj) {
        float bv = kS[j0 + jj][d];
        acc[0][jj] = fmaf(a0, bv, acc[0][jj]);
        acc[1][jj] = fmaf(a1, bv, acc[1][jj]);
        acc[2][jj] = fmaf(a2, bv, acc[2][jj]);
        acc[3][jj] = fmaf(a3, bv, acc[3][jj]);
      }
    }
  }
  __syncthreads();
#pragma unroll
  for (int ii = 0; ii < 4; ++ii)
#pragma unroll
    for (int jj = 0; jj < 4; ++jj) {
      int i = i0 + ii, j = j0 + jj;
      attnS[i][j] = (i >= j) ? acc[ii][jj] * gpow[i - j] : 0.0f;
    }
  float (*vS)[65] = qS;
  for (int vb = 0; vb < 8; ++vb) {
    __syncthreads();
#pragma unroll
    for (int r = 0; r < 16; ++r) {
      int idx = t + 256 * r;
      int row = idx >> 6, col = idx & 63;
      vS[row][col] = v[baseV + (size_t)row * VDIM + vb * 64 + col];
    }
    __syncthreads();
    float oa[4][4] = {};
    for (int j = 0; j < 64; ++j) {
      float a0 = attnS[i0][j], a1 = attnS[i0 + 1][j], a2 = attnS[i0 + 2][j], a3 = attnS[i0 + 3][j];
#pragma unroll
      for (int jj = 0; jj < 4; ++jj) {
        float bv = vS[j][j0 + jj];
        oa[0][jj] = fmaf(a0, bv, oa[0][jj]);
        oa[1][jj] = fmaf(a1, bv, oa[1][jj]);
        oa[2][jj] = fmaf(a2, bv, oa[2][jj]);
        oa[3][jj] = fmaf(a3, bv, oa[3][jj]);
      }
    }
#pragma unroll
    for (int ii = 0; ii < 4; ++ii)
#pragma unroll
      for (int jj = 0; jj < 4; ++jj)
        o[baseV + (size_t)(i0 + ii) * VDIM + vb * 64 + j0 + jj] = oa[ii][jj];
  }
}

// ---------------- Retention pass 2: inter-chunk scan, dk-split x4 ------------
// Grid: (vt=8, h=4, b*4+dkg=16) = 512 WGs (2/CU). State recurrence is
// row-independent in dk, so each WG owns a 64(dk) x 64(dv) state tile.
// o_inter reduces over dk across the 4 dkg WGs -> atomicAdd into o.
// Thread t: state row dk=(t&63), dv cols [(t>>6)*16, +16) -> S[16] regs.
__global__ __launch_bounds__(256) void retn_inter(const float* __restrict__ q,
                                                  const float* __restrict__ k,
                                                  const float* __restrict__ v,
                                                  float* __restrict__ o) {
  const int vt  = blockIdx.x;
  const int h   = blockIdx.y;
  const int b   = blockIdx.z & 3;
  const int dkg = blockIdx.z >> 2;
  const int t = threadIdx.x;
  __shared__ float gpow[65];
  __shared__ float vS[64][65];
  __shared__ float sS[64][65];
  __shared__ float qS[64][65];
  if (t <= 64) {
    float gamma = 1.0f - exp2f(-5.0f - (float)h);
    gpow[t] = powf(gamma, (float)t);
  }
  __syncthreads();
  const float gC = gpow[64];
  const size_t baseQ = (size_t)(b * T_SEQ) * KDIM + h * HK + dkg * 64;
  const size_t baseV = (size_t)(b * T_SEQ) * VDIM + h * HV + vt * 64;
  const int dk = t & 63;          // state row within this WG's dk group
  const int c0 = (t >> 6) * 16;   // this thread's dv col range
  const int i0 = (t >> 4) * 4;    // o-tile row base
  const int v0 = (t & 15) * 4;    // o-tile col base
  float S[16];
#pragma unroll
  for (int c = 0; c < 16; ++c) S[c] = 0.f;

  for (int n = 0; n < 32; ++n) {
    const int t0 = n * 64;
    __syncthreads();   // prev iteration's vS/qS/sS readers done
    // stage V (64 x 64 dv) and decayed Q (64 x 64 dk), publish S to LDS
#pragma unroll
    for (int r = 0; r < 16; ++r) {
      int idx = t + 256 * r;
      int row = idx >> 6, col = idx & 63;
      vS[row][col] = v[baseV + (size_t)(t0 + row) * VDIM + col];
      qS[row][col] = q[baseQ + (size_t)(t0 + row) * KDIM + col] * gpow[row + 1];
    }
#pragma unroll
    for (int c = 0; c < 16; ++c) sS[dk][c0 + c] = S[c];
    __syncthreads();
    // o_inter tile (64 x 64), reduce over this WG's 64 dk rows
    float oa[4][4] = {};
    for (int d = 0; d < 64; ++d) {
      float a0 = qS[i0][d], a1 = qS[i0 + 1][d], a2 = qS[i0 + 2][d], a3 = qS[i0 + 3][d];
#pragma unroll
      for (int jj = 0; jj < 4; ++jj) {
        float sv = sS[d][v0 + jj];
        oa[0][jj] = fmaf(a0, sv, oa[0][jj]);
        oa[1][jj] = fmaf(a1, sv, oa[1][jj]);
        oa[2][jj] = fmaf(a2, sv, oa[2][jj]);
        oa[3][jj] = fmaf(a3, sv, oa[3][jj]);
      }
    }
#pragma unroll
    for (int ii = 0; ii < 4; ++ii) {
      size_t addr = baseV + (size_t)(t0 + i0 + ii) * VDIM + v0;
#pragma unroll
      for (int jj = 0; jj < 4; ++jj)
        atomicAdd(&o[addr + jj], oa[ii][jj]);
    }
    // state update: S = gC*S + sum_j kdec[j] * K[j][dk] * V[j][c]
#pragma unroll
    for (int c = 0; c < 16; ++c) S[c] *= gC;
    for (int j = 0; j < 64; ++j) {
      float kval = k[baseQ + (size_t)(t0 + j) * KDIM + dk] * gpow[63 - j];
#pragma unroll
      for (int c = 0; c < 16; ++c) S[c] = fmaf(kval, vS[j][c0 + c], S[c]);
    }
  }
}

// ---------------- RMS group-norm over HEAD_V + SiLU(g) gate (in-place) -------
__global__ __launch_bounds__(256) void norm_gate(float* __restrict__ o,
                                                 const float* __restrict__ g,
                                                 const float* __restrict__ gnw) {
  const int row = blockIdx.x;                 // (b*T + t)*H + h, 32768 rows
  const size_t base = (size_t)row * 512;
  const int t = threadIdx.x;
  float x0 = o[base + t], x1 = o[base + t + 256];
  float ss = x0 * x0 + x1 * x1;
#pragma unroll
  for (int off = 32; off > 0; off >>= 1) ss += __shfl_down(ss, off, 64);
  __shared__ float wsum[4];
  if ((t & 63) == 0) wsum[t >> 6] = ss;
  __syncthreads();
  float tot = wsum[0] + wsum[1] + wsum[2] + wsum[3];
  float scale = rsqrtf(tot * (1.0f / 512.0f) + 1e-5f);
  float g0 = g[base + t], g1 = g[base + t + 256];
  o[base + t]       = x0 * scale * gnw[t]       * (g0 / (1.0f + expf(-g0)));
  o[base + t + 256] = x1 * scale * gnw[t + 256] * (g1 / (1.0f + expf(-g1)));
}

extern "C" void kernel_launch(void* const* d_in, const int* in_sizes, int n_in,
                              void* d_out, int out_size, void* d_ws, size_t ws_size,
                              hipStream_t stream) {
  const float* x   = (const float*)d_in[0];
  const float* Wq  = (const float*)d_in[1];
  const float* Wk  = (const float*)d_in[2];
  const float* Wv  = (const float*)d_in[3];
  const float* Wg  = (const float*)d_in[4];
  const float* Wo  = (const float*)d_in[5];
  const float* gnw = (const float*)d_in[6];
  float* out = (float*)d_out;

  // workspace layout (192 MiB): [q 32][k 32][v 64][o 64]; g aliases q+k
  float* q  = (float*)d_ws;                       //  8192*1024
  float* kk = q  + (size_t)8192 * 1024;           //  8192*1024
  float* v  = kk + (size_t)8192 * 1024;           //  8192*2048
  float* o  = v  + (size_t)8192 * 2048;           //  8192*2048
  float* g  = q;                                  //  8192*2048 (aliases q,k)

  dim3 blk(256);
  gemm_f32<<<dim3(8, 64),  blk, 0, stream>>>(x, Wq, q,  8192, 1024, 1024);
  gemm_f32<<<dim3(8, 64),  blk, 0, stream>>>(x, Wk, kk, 8192, 1024, 1024);
  gemm_f32<<<dim3(16, 64), blk, 0, stream>>>(x, Wv, v,  8192, 2048, 1024);
  rope_kernel<<<dim3(16384), blk, 0, stream>>>(q, kk);
  retn_intra<<<dim3(32, 4, 4),  blk, 0, stream>>>(q, kk, v, o);
  retn_inter<<<dim3(8, 4, 16),  blk, 0, stream>>>(q, kk, v, o);
  gemm_f32<<<dim3(16, 64), blk, 0, stream>>>(x, Wg, g,  8192, 2048, 1024);
  norm_gate<<<dim3(32768), blk, 0, stream>>>(o, g, gnw);
  gemm_f32<<<dim3(8, 64),  blk, 0, stream>>>(o, Wo, out, 8192, 1024, 2048);
}

// Round 5
// 1740.924 us; speedup vs baseline: 1.8056x; 1.6327x over previous
//
#include <hip/hip_runtime.h>
#include <cstdint>
#include <cstddef>

#define T_SEQ 2048
#define DM    1024
#define HK    256
#define HV    512
#define NH    4
#define KDIM  1024
#define VDIM  2048

typedef __attribute__((ext_vector_type(8))) short bf16x8;
typedef __attribute__((ext_vector_type(4))) float f32x4;
#define AS1 __attribute__((address_space(1)))
#define AS3 __attribute__((address_space(3)))

// ---------------- f32 -> (hi, lo) bf16 split (RNE), vectorized x4 ------------
static __device__ inline unsigned short f2bf(float f) {
  unsigned u = __float_as_uint(f);
  unsigned rnd = 0x7fffu + ((u >> 16) & 1u);
  return (unsigned short)((u + rnd) >> 16);
}
static __device__ inline float bf2f(unsigned short h) {
  unsigned u = ((unsigned)h) << 16;
  return __uint_as_float(u);
}

__global__ __launch_bounds__(256) void cast_split(const float* __restrict__ in,
                                                  unsigned short* __restrict__ hi,
                                                  unsigned short* __restrict__ lo,
                                                  int n4) {
  int i = blockIdx.x * 256 + threadIdx.x;
  if (i >= n4) return;
  float4 v = ((const float4*)in)[i];
  ushort4 h, l;
  h.x = f2bf(v.x); l.x = f2bf(v.x - bf2f(h.x));
  h.y = f2bf(v.y); l.y = f2bf(v.y - bf2f(h.y));
  h.z = f2bf(v.z); l.z = f2bf(v.z - bf2f(h.z));
  h.w = f2bf(v.w); l.w = f2bf(v.w - bf2f(h.w));
  ((ushort4*)hi)[i] = h;
  ((ushort4*)lo)[i] = l;
}

// -------- split-precision bf16 MFMA GEMM: C = A @ W^T, A=Ah+Al, W=Wh+Wl ------
// C ~= Ah*Wh + Ah*Wl + Al*Wh (f32 accumulate; lo*lo term ~2^-16 rel, dropped).
// 128x128 tile, BK=32, 4 waves 2x2, wave = 64x64 = 4x4 16x16x32 frags.
__global__ __launch_bounds__(256) void gemm_bf16s(const unsigned short* __restrict__ Ah,
                                                  const unsigned short* __restrict__ Al,
                                                  const unsigned short* __restrict__ Wh,
                                                  const unsigned short* __restrict__ Wl,
                                                  float* __restrict__ C,
                                                  int M, int N, int K) {
  __shared__ unsigned short AhS[128 * 32];
  __shared__ unsigned short AlS[128 * 32];
  __shared__ unsigned short WhS[128 * 32];
  __shared__ unsigned short WlS[128 * 32];
  const int t = threadIdx.x;
  const int l = t & 63;
  const int w = t >> 6;
  const int bm = blockIdx.y * 128;
  const int bn = blockIdx.x * 128;
  const int wm = (w >> 1) * 64;
  const int wn = (w & 1) * 64;

  f32x4 acc[4][4];
#pragma unroll
  for (int i = 0; i < 4; ++i)
#pragma unroll
    for (int j = 0; j < 4; ++j)
#pragma unroll
      for (int r = 0; r < 4; ++r) acc[i][j][r] = 0.f;

  // staging: wave w covers tile rows [w*32, +32); one instr stages 16 rows
  // (64 lanes x 16 B; lane l -> row l>>2, col (l&3)*8).
  const int srow = w * 32 + (l >> 2);
  const int scol = (l & 3) * 8;
  const size_t gOffA = (size_t)(bm + srow) * K + scol;
  const size_t gOffW = (size_t)(bn + srow) * K + scol;
  const size_t rowStep = (size_t)16 * K;
  unsigned short* lAh0 = &AhS[(w * 32) * 32];
  unsigned short* lAh1 = &AhS[(w * 32 + 16) * 32];
  unsigned short* lAl0 = &AlS[(w * 32) * 32];
  unsigned short* lAl1 = &AlS[(w * 32 + 16) * 32];
  unsigned short* lWh0 = &WhS[(w * 32) * 32];
  unsigned short* lWh1 = &WhS[(w * 32 + 16) * 32];
  unsigned short* lWl0 = &WlS[(w * 32) * 32];
  unsigned short* lWl1 = &WlS[(w * 32 + 16) * 32];

  for (int k0 = 0; k0 < K; k0 += 32) {
    __syncthreads();                       // prev iter's ds_reads done
    __builtin_amdgcn_global_load_lds((const AS1 void*)(Ah + gOffA + k0),           (AS3 void*)lAh0, 16, 0, 0);
    __builtin_amdgcn_global_load_lds((const AS1 void*)(Ah + gOffA + rowStep + k0), (AS3 void*)lAh1, 16, 0, 0);
    __builtin_amdgcn_global_load_lds((const AS1 void*)(Al + gOffA + k0),           (AS3 void*)lAl0, 16, 0, 0);
    __builtin_amdgcn_global_load_lds((const AS1 void*)(Al + gOffA + rowStep + k0), (AS3 void*)lAl1, 16, 0, 0);
    __builtin_amdgcn_global_load_lds((const AS1 void*)(Wh + gOffW + k0),           (AS3 void*)lWh0, 16, 0, 0);
    __builtin_amdgcn_global_load_lds((const AS1 void*)(Wh + gOffW + rowStep + k0), (AS3 void*)lWh1, 16, 0, 0);
    __builtin_amdgcn_global_load_lds((const AS1 void*)(Wl + gOffW + k0),           (AS3 void*)lWl0, 16, 0, 0);
    __builtin_amdgcn_global_load_lds((const AS1 void*)(Wl + gOffW + rowStep + k0), (AS3 void*)lWl1, 16, 0, 0);
    __syncthreads();                       // drains vmcnt(0): staging complete

    bf16x8 ah[4], al[4], bh[4], bl[4];
#pragma unroll
    for (int i = 0; i < 4; ++i) {
      int aoff = (wm + i * 16 + (l & 15)) * 32 + (l >> 4) * 8;
      int boff = (wn + i * 16 + (l & 15)) * 32 + (l >> 4) * 8;
      ah[i] = *(const bf16x8*)&AhS[aoff];
      al[i] = *(const bf16x8*)&AlS[aoff];
      bh[i] = *(const bf16x8*)&WhS[boff];
      bl[i] = *(const bf16x8*)&WlS[boff];
    }
#pragma unroll
    for (int i = 0; i < 4; ++i)
#pragma unroll
      for (int j = 0; j < 4; ++j) {
        acc[i][j] = __builtin_amdgcn_mfma_f32_16x16x32_bf16(ah[i], bh[j], acc[i][j], 0, 0, 0);
        acc[i][j] = __builtin_amdgcn_mfma_f32_16x16x32_bf16(ah[i], bl[j], acc[i][j], 0, 0, 0);
        acc[i][j] = __builtin_amdgcn_mfma_f32_16x16x32_bf16(al[i], bh[j], acc[i][j], 0, 0, 0);
      }
  }

  // epilogue: C/D layout col=lane&15, row=(lane>>4)*4+reg
  const int cr = (l >> 4) * 4;
  const int cc = l & 15;
#pragma unroll
  for (int i = 0; i < 4; ++i)
#pragma unroll
    for (int j = 0; j < 4; ++j)
#pragma unroll
      for (int r = 0; r < 4; ++r)
        C[(size_t)(bm + wm + i * 16 + cr + r) * N + (bn + wn + j * 16 + cc)] = acc[i][j][r];
}

// ---------------- RoPE (in-place on q and k), q also scaled by HK^-0.5 -------
__global__ __launch_bounds__(256) void rope_kernel(float* __restrict__ q,
                                                   float* __restrict__ k) {
  int idx = blockIdx.x * 256 + threadIdx.x;     // over B*T*H*128 = 4,194,304
  int f  = idx & 127;
  int h  = (idx >> 7) & 3;
  int tt = (idx >> 9) & 2047;
  int b  = idx >> 20;
  size_t a0 = ((size_t)(b * T_SEQ + tt)) * KDIM + h * HK + f;
  size_t a1 = a0 + 128;
  float invf = powf(10000.0f, -(float)f * (1.0f / 128.0f));
  float ang  = (float)tt * invf;
  float s, c;
  sincosf(ang, &s, &c);
  float q1 = q[a0], q2 = q[a1];
  q[a0] = (q1 * c - q2 * s) * 0.0625f;
  q[a1] = (q2 * c + q1 * s) * 0.0625f;
  float k1 = k[a0], k2 = k[a1];
  k[a0] = k1 * c - k2 * s;
  k[a1] = k2 * c + k1 * s;
}

// ---------------- Retention pass 1: intra-chunk (fully parallel) -------------
__global__ __launch_bounds__(256) void retn_intra(const float* __restrict__ q,
                                                  const float* __restrict__ k,
                                                  const float* __restrict__ v,
                                                  float* __restrict__ o) {
  const int n = blockIdx.x, h = blockIdx.y, b = blockIdx.z;
  const int t = threadIdx.x;
  const int t0 = n * 64;
  __shared__ float gpow[65];
  __shared__ float qS[64][65];
  __shared__ float kS[64][65];
  __shared__ float attnS[64][65];
  if (t <= 64) {
    float gamma = 1.0f - exp2f(-5.0f - (float)h);
    gpow[t] = powf(gamma, (float)t);
  }
  const size_t baseQK = (size_t)(b * T_SEQ + t0) * KDIM + h * HK;
  const size_t baseV  = (size_t)(b * T_SEQ + t0) * VDIM + h * HV;
  const int i0 = (t >> 4) * 4;
  const int j0 = (t & 15) * 4;
  float acc[4][4] = {};
  for (int s = 0; s < 4; ++s) {              // dk slices of 64
    __syncthreads();
#pragma unroll
    for (int r = 0; r < 16; ++r) {
      int idx = t + 256 * r;
      int row = idx >> 6, col = idx & 63;
      qS[row][col] = q[baseQK + (size_t)row * KDIM + s * 64 + col];
      kS[row][col] = k[baseQK + (size_t)row * KDIM + s * 64 + col];
    }
    __syncthreads();
    for (int d = 0; d < 64; ++d) {
      float a0 = qS[i0][d], a1 = qS[i0 + 1][d], a2 = qS[i0 + 2][d], a3 = qS[i0 + 3][d];
#pragma unroll
      for (int jj = 0; jj < 4; ++jj) {
        float bv = kS[j0 + jj][d];
        acc[0][jj] = fmaf(a0, bv, acc[0][jj]);
        acc[1][jj] = fmaf(a1, bv, acc[1][jj]);
        acc[2][jj] = fmaf(a2, bv, acc[2][jj]);
        acc[3][jj] = fmaf(a3, bv, acc[3][jj]);
      }
    }
  }
  __syncthreads();
#pragma unroll
  for (int ii = 0; ii < 4; ++ii)
#pragma unroll
    for (int jj = 0; jj < 4; ++jj) {
      int i = i0 + ii, j = j0 + jj;
      attnS[i][j] = (i >= j) ? acc[ii][jj] * gpow[i - j] : 0.0f;
    }
  float (*vS)[65] = qS;
  for (int vb = 0; vb < 8; ++vb) {
    __syncthreads();
#pragma unroll
    for (int r = 0; r < 16; ++r) {
      int idx = t + 256 * r;
      int row = idx >> 6, col = idx & 63;
      vS[row][col] = v[baseV + (size_t)row * VDIM + vb * 64 + col];
    }
    __syncthreads();
    float oa[4][4] = {};
    for (int j = 0; j < 64; ++j) {
      float a0 = attnS[i0][j], a1 = attnS[i0 + 1][j], a2 = attnS[i0 + 2][j], a3 = attnS[i0 + 3][j];
#pragma unroll
      for (int jj = 0; jj < 4; ++jj) {
        float bv = vS[j][j0 + jj];
        oa[0][jj] = fmaf(a0, bv, oa[0][jj]);
        oa[1][jj] = fmaf(a1, bv, oa[1][jj]);
        oa[2][jj] = fmaf(a2, bv, oa[2][jj]);
        oa[3][jj] = fmaf(a3, bv, oa[3][jj]);
      }
    }
#pragma unroll
    for (int ii = 0; ii < 4; ++ii)
#pragma unroll
      for (int jj = 0; jj < 4; ++jj)
        o[baseV + (size_t)(i0 + ii) * VDIM + vb * 64 + j0 + jj] = oa[ii][jj];
  }
}

// ---------------- Retention pass 2: inter-chunk scan, dk-split x4 ------------
__global__ __launch_bounds__(256) void retn_inter(const float* __restrict__ q,
                                                  const float* __restrict__ k,
                                                  const float* __restrict__ v,
                                                  float* __restrict__ o) {
  const int vt  = blockIdx.x;
  const int h   = blockIdx.y;
  const int b   = blockIdx.z & 3;
  const int dkg = blockIdx.z >> 2;
  const int t = threadIdx.x;
  __shared__ float gpow[65];
  __shared__ float vS[64][65];
  __shared__ float sS[64][65];
  __shared__ float qS[64][65];
  if (t <= 64) {
    float gamma = 1.0f - exp2f(-5.0f - (float)h);
    gpow[t] = powf(gamma, (float)t);
  }
  __syncthreads();
  const float gC = gpow[64];
  const size_t baseQ = (size_t)(b * T_SEQ) * KDIM + h * HK + dkg * 64;
  const size_t baseV = (size_t)(b * T_SEQ) * VDIM + h * HV + vt * 64;
  const int dk = t & 63;
  const int c0 = (t >> 6) * 16;
  const int i0 = (t >> 4) * 4;
  const int v0 = (t & 15) * 4;
  float S[16];
#pragma unroll
  for (int c = 0; c < 16; ++c) S[c] = 0.f;

  for (int n = 0; n < 32; ++n) {
    const int t0 = n * 64;
    __syncthreads();
#pragma unroll
    for (int r = 0; r < 16; ++r) {
      int idx = t + 256 * r;
      int row = idx >> 6, col = idx & 63;
      vS[row][col] = v[baseV + (size_t)(t0 + row) * VDIM + col];
      qS[row][col] = q[baseQ + (size_t)(t0 + row) * KDIM + col] * gpow[row + 1];
    }
#pragma unroll
    for (int c = 0; c < 16; ++c) sS[dk][c0 + c] = S[c];
    __syncthreads();
    float oa[4][4] = {};
    for (int d = 0; d < 64; ++d) {
      float a0 = qS[i0][d], a1 = qS[i0 + 1][d], a2 = qS[i0 + 2][d], a3 = qS[i0 + 3][d];
#pragma unroll
      for (int jj = 0; jj < 4; ++jj) {
        float sv = sS[d][v0 + jj];
        oa[0][jj] = fmaf(a0, sv, oa[0][jj]);
        oa[1][jj] = fmaf(a1, sv, oa[1][jj]);
        oa[2][jj] = fmaf(a2, sv, oa[2][jj]);
        oa[3][jj] = fmaf(a3, sv, oa[3][jj]);
      }
    }
#pragma unroll
    for (int ii = 0; ii < 4; ++ii) {
      size_t addr = baseV + (size_t)(t0 + i0 + ii) * VDIM + v0;
#pragma unroll
      for (int jj = 0; jj < 4; ++jj)
        atomicAdd(&o[addr + jj], oa[ii][jj]);
    }
#pragma unroll
    for (int c = 0; c < 16; ++c) S[c] *= gC;
    for (int j = 0; j < 64; ++j) {
      float kval = k[baseQ + (size_t)(t0 + j) * KDIM + dk] * gpow[63 - j];
#pragma unroll
      for (int c = 0; c < 16; ++c) S[c] = fmaf(kval, vS[j][c0 + c], S[c]);
    }
  }
}

// ---------------- RMS group-norm over HEAD_V + SiLU(g) gate (in-place) -------
__global__ __launch_bounds__(256) void norm_gate(float* __restrict__ o,
                                                 const float* __restrict__ g,
                                                 const float* __restrict__ gnw) {
  const int row = blockIdx.x;
  const size_t base = (size_t)row * 512;
  const int t = threadIdx.x;
  float x0 = o[base + t], x1 = o[base + t + 256];
  float ss = x0 * x0 + x1 * x1;
#pragma unroll
  for (int off = 32; off > 0; off >>= 1) ss += __shfl_down(ss, off, 64);
  __shared__ float wsum[4];
  if ((t & 63) == 0) wsum[t >> 6] = ss;
  __syncthreads();
  float tot = wsum[0] + wsum[1] + wsum[2] + wsum[3];
  float scale = rsqrtf(tot * (1.0f / 512.0f) + 1e-5f);
  float g0 = g[base + t], g1 = g[base + t + 256];
  o[base + t]       = x0 * scale * gnw[t]       * (g0 / (1.0f + expf(-g0)));
  o[base + t + 256] = x1 * scale * gnw[t + 256] * (g1 / (1.0f + expf(-g1)));
}

extern "C" void kernel_launch(void* const* d_in, const int* in_sizes, int n_in,
                              void* d_out, int out_size, void* d_ws, size_t ws_size,
                              hipStream_t stream) {
  const float* x   = (const float*)d_in[0];
  const float* Wq  = (const float*)d_in[1];
  const float* Wk  = (const float*)d_in[2];
  const float* Wv  = (const float*)d_in[3];
  const float* Wg  = (const float*)d_in[4];
  const float* Wo  = (const float*)d_in[5];
  const float* gnw = (const float*)d_in[6];
  float* out = (float*)d_out;

  // workspace = 256 MiB exactly (round-1 proved available):
  // [q 32][k 32][v 64][o 64][x-splits 32][W-splits 32]
  // o-splits (64) alias dead v; g (64) aliases dead q+k.
  const size_t M8 = (size_t)8192;
  float* q  = (float*)d_ws;                        // 8M f32
  float* kk = q  + M8 * 1024;                      // 8M f32
  float* v  = kk + M8 * 1024;                      // 16M f32
  float* o  = v  + M8 * 2048;                      // 16M f32
  unsigned short* xh  = (unsigned short*)(o + M8 * 2048);  // 8M bf16
  unsigned short* xl  = xh  + M8 * 1024;           // 8M
  unsigned short* wqh = xl  + M8 * 1024;           // 1M
  unsigned short* wql = wqh + (size_t)1024 * 1024;
  unsigned short* wkh = wql + (size_t)1024 * 1024;
  unsigned short* wkl = wkh + (size_t)1024 * 1024;
  unsigned short* wvh = wkl + (size_t)1024 * 1024; // 2M each below
  unsigned short* wvl = wvh + (size_t)2048 * 1024;
  unsigned short* wgh = wvl + (size_t)2048 * 1024;
  unsigned short* wgl = wgh + (size_t)2048 * 1024;
  unsigned short* woh = wgl + (size_t)2048 * 1024;
  unsigned short* wol = woh + (size_t)2048 * 1024;
  unsigned short* oh  = (unsigned short*)v;        // 16M bf16, aliases dead v
  unsigned short* ol  = oh + M8 * 2048;            // 16M bf16
  float* g = q;                                    // 16M f32, aliases dead q+k

  dim3 blk(256);
  cast_split<<<dim3(8192), blk, 0, stream>>>(x,  xh,  xl,  2097152);
  cast_split<<<dim3(1024), blk, 0, stream>>>(Wq, wqh, wql, 262144);
  cast_split<<<dim3(1024), blk, 0, stream>>>(Wk, wkh, wkl, 262144);
  cast_split<<<dim3(2048), blk, 0, stream>>>(Wv, wvh, wvl, 524288);
  cast_split<<<dim3(2048), blk, 0, stream>>>(Wg, wgh, wgl, 524288);
  cast_split<<<dim3(2048), blk, 0, stream>>>(Wo, woh, wol, 524288);

  gemm_bf16s<<<dim3(8, 64),  blk, 0, stream>>>(xh, xl, wqh, wql, q,  8192, 1024, 1024);
  gemm_bf16s<<<dim3(8, 64),  blk, 0, stream>>>(xh, xl, wkh, wkl, kk, 8192, 1024, 1024);
  gemm_bf16s<<<dim3(16, 64), blk, 0, stream>>>(xh, xl, wvh, wvl, v,  8192, 2048, 1024);
  rope_kernel<<<dim3(16384), blk, 0, stream>>>(q, kk);
  retn_intra<<<dim3(32, 4, 4),  blk, 0, stream>>>(q, kk, v, o);
  retn_inter<<<dim3(8, 4, 16),  blk, 0, stream>>>(q, kk, v, o);
  gemm_bf16s<<<dim3(16, 64), blk, 0, stream>>>(xh, xl, wgh, wgl, g, 8192, 2048, 1024);
  norm_gate<<<dim3(32768), blk, 0, stream>>>(o, g, gnw);
  cast_split<<<dim3(16384), blk, 0, stream>>>(o, oh, ol, 4194304);
  gemm_bf16s<<<dim3(8, 64),  blk, 0, stream>>>(oh, ol, woh, wol, out, 8192, 1024, 2048);
}

// Round 6
// 1575.705 us; speedup vs baseline: 1.9949x; 1.1049x over previous
//
#include <hip/hip_runtime.h>
#include <cstdint>
#include <cstddef>

#define T_SEQ 2048
#define DM    1024
#define HK    256
#define HV    512
#define NH    4
#define KDIM  1024
#define VDIM  2048

typedef __attribute__((ext_vector_type(8))) short bf16x8;
typedef __attribute__((ext_vector_type(4))) float f32x4;
#define AS1 __attribute__((address_space(1)))
#define AS3 __attribute__((address_space(3)))

// ---------------- f32 -> (hi, lo) bf16 split (RNE), vectorized x4 ------------
static __device__ inline unsigned short f2bf(float f) {
  unsigned u = __float_as_uint(f);
  unsigned rnd = 0x7fffu + ((u >> 16) & 1u);
  return (unsigned short)((u + rnd) >> 16);
}
static __device__ inline float bf2f(unsigned short h) {
  unsigned u = ((unsigned)h) << 16;
  return __uint_as_float(u);
}

__global__ __launch_bounds__(256) void cast_split(const float* __restrict__ in,
                                                  unsigned short* __restrict__ hi,
                                                  unsigned short* __restrict__ lo,
                                                  int n4) {
  int i = blockIdx.x * 256 + threadIdx.x;
  if (i >= n4) return;
  float4 v = ((const float4*)in)[i];
  ushort4 h, l;
  h.x = f2bf(v.x); l.x = f2bf(v.x - bf2f(h.x));
  h.y = f2bf(v.y); l.y = f2bf(v.y - bf2f(h.y));
  h.z = f2bf(v.z); l.z = f2bf(v.z - bf2f(h.z));
  h.w = f2bf(v.w); l.w = f2bf(v.w - bf2f(h.w));
  ((ushort4*)hi)[i] = h;
  ((ushort4*)lo)[i] = l;
}

// -------- split-precision bf16 MFMA GEMM: C = A @ W^T, A=Ah+Al, W=Wh+Wl ------
// C ~= Ah*Wh + Ah*Wl + Al*Wh (f32 accumulate; lo*lo term ~2^-16 rel, dropped).
// 128x128 tile, BK=32, 4 waves 2x2, wave = 64x64 = 4x4 16x16x32 frags.
__global__ __launch_bounds__(256) void gemm_bf16s(const unsigned short* __restrict__ Ah,
                                                  const unsigned short* __restrict__ Al,
                                                  const unsigned short* __restrict__ Wh,
                                                  const unsigned short* __restrict__ Wl,
                                                  float* __restrict__ C,
                                                  int M, int N, int K) {
  __shared__ unsigned short AhS[128 * 32];
  __shared__ unsigned short AlS[128 * 32];
  __shared__ unsigned short WhS[128 * 32];
  __shared__ unsigned short WlS[128 * 32];
  const int t = threadIdx.x;
  const int l = t & 63;
  const int w = t >> 6;
  const int bm = blockIdx.y * 128;
  const int bn = blockIdx.x * 128;
  const int wm = (w >> 1) * 64;
  const int wn = (w & 1) * 64;

  f32x4 acc[4][4];
#pragma unroll
  for (int i = 0; i < 4; ++i)
#pragma unroll
    for (int j = 0; j < 4; ++j)
#pragma unroll
      for (int r = 0; r < 4; ++r) acc[i][j][r] = 0.f;

  const int srow = w * 32 + (l >> 2);
  const int scol = (l & 3) * 8;
  const size_t gOffA = (size_t)(bm + srow) * K + scol;
  const size_t gOffW = (size_t)(bn + srow) * K + scol;
  const size_t rowStep = (size_t)16 * K;
  unsigned short* lAh0 = &AhS[(w * 32) * 32];
  unsigned short* lAh1 = &AhS[(w * 32 + 16) * 32];
  unsigned short* lAl0 = &AlS[(w * 32) * 32];
  unsigned short* lAl1 = &AlS[(w * 32 + 16) * 32];
  unsigned short* lWh0 = &WhS[(w * 32) * 32];
  unsigned short* lWh1 = &WhS[(w * 32 + 16) * 32];
  unsigned short* lWl0 = &WlS[(w * 32) * 32];
  unsigned short* lWl1 = &WlS[(w * 32 + 16) * 32];

  for (int k0 = 0; k0 < K; k0 += 32) {
    __syncthreads();
    __builtin_amdgcn_global_load_lds((const AS1 void*)(Ah + gOffA + k0),           (AS3 void*)lAh0, 16, 0, 0);
    __builtin_amdgcn_global_load_lds((const AS1 void*)(Ah + gOffA + rowStep + k0), (AS3 void*)lAh1, 16, 0, 0);
    __builtin_amdgcn_global_load_lds((const AS1 void*)(Al + gOffA + k0),           (AS3 void*)lAl0, 16, 0, 0);
    __builtin_amdgcn_global_load_lds((const AS1 void*)(Al + gOffA + rowStep + k0), (AS3 void*)lAl1, 16, 0, 0);
    __builtin_amdgcn_global_load_lds((const AS1 void*)(Wh + gOffW + k0),           (AS3 void*)lWh0, 16, 0, 0);
    __builtin_amdgcn_global_load_lds((const AS1 void*)(Wh + gOffW + rowStep + k0), (AS3 void*)lWh1, 16, 0, 0);
    __builtin_amdgcn_global_load_lds((const AS1 void*)(Wl + gOffW + k0),           (AS3 void*)lWl0, 16, 0, 0);
    __builtin_amdgcn_global_load_lds((const AS1 void*)(Wl + gOffW + rowStep + k0), (AS3 void*)lWl1, 16, 0, 0);
    __syncthreads();

    bf16x8 ah[4], al[4], bh[4], bl[4];
#pragma unroll
    for (int i = 0; i < 4; ++i) {
      int aoff = (wm + i * 16 + (l & 15)) * 32 + (l >> 4) * 8;
      int boff = (wn + i * 16 + (l & 15)) * 32 + (l >> 4) * 8;
      ah[i] = *(const bf16x8*)&AhS[aoff];
      al[i] = *(const bf16x8*)&AlS[aoff];
      bh[i] = *(const bf16x8*)&WhS[boff];
      bl[i] = *(const bf16x8*)&WlS[boff];
    }
#pragma unroll
    for (int i = 0; i < 4; ++i)
#pragma unroll
      for (int j = 0; j < 4; ++j) {
        acc[i][j] = __builtin_amdgcn_mfma_f32_16x16x32_bf16(ah[i], bh[j], acc[i][j], 0, 0, 0);
        acc[i][j] = __builtin_amdgcn_mfma_f32_16x16x32_bf16(ah[i], bl[j], acc[i][j], 0, 0, 0);
        acc[i][j] = __builtin_amdgcn_mfma_f32_16x16x32_bf16(al[i], bh[j], acc[i][j], 0, 0, 0);
      }
  }

  const int cr = (l >> 4) * 4;
  const int cc = l & 15;
#pragma unroll
  for (int i = 0; i < 4; ++i)
#pragma unroll
    for (int j = 0; j < 4; ++j)
#pragma unroll
      for (int r = 0; r < 4; ++r)
        C[(size_t)(bm + wm + i * 16 + cr + r) * N + (bn + wn + j * 16 + cc)] = acc[i][j][r];
}

// ---------------- RoPE (in-place on q and k), q also scaled by HK^-0.5 -------
__global__ __launch_bounds__(256) void rope_kernel(float* __restrict__ q,
                                                   float* __restrict__ k) {
  int idx = blockIdx.x * 256 + threadIdx.x;     // over B*T*H*128 = 4,194,304
  int f  = idx & 127;
  int h  = (idx >> 7) & 3;
  int tt = (idx >> 9) & 2047;
  int b  = idx >> 20;
  size_t a0 = ((size_t)(b * T_SEQ + tt)) * KDIM + h * HK + f;
  size_t a1 = a0 + 128;
  float invf = powf(10000.0f, -(float)f * (1.0f / 128.0f));
  float ang  = (float)tt * invf;
  float s, c;
  sincosf(ang, &s, &c);
  float q1 = q[a0], q2 = q[a1];
  q[a0] = (q1 * c - q2 * s) * 0.0625f;
  q[a1] = (q2 * c + q1 * s) * 0.0625f;
  float k1 = k[a0], k2 = k[a1];
  k[a0] = k1 * c - k2 * s;
  k[a1] = k2 * c + k1 * s;
}

// ---------------- Retention pass 1: intra-chunk (fully parallel) -------------
__global__ __launch_bounds__(256) void retn_intra(const float* __restrict__ q,
                                                  const float* __restrict__ k,
                                                  const float* __restrict__ v,
                                                  float* __restrict__ o) {
  const int n = blockIdx.x, h = blockIdx.y, b = blockIdx.z;
  const int t = threadIdx.x;
  const int t0 = n * 64;
  __shared__ float gpow[65];
  __shared__ float qS[64][65];
  __shared__ float kS[64][65];
  __shared__ float attnS[64][65];
  if (t <= 64) {
    float gamma = 1.0f - exp2f(-5.0f - (float)h);
    gpow[t] = powf(gamma, (float)t);
  }
  const size_t baseQK = (size_t)(b * T_SEQ + t0) * KDIM + h * HK;
  const size_t baseV  = (size_t)(b * T_SEQ + t0) * VDIM + h * HV;
  const int i0 = (t >> 4) * 4;
  const int j0 = (t & 15) * 4;
  float acc[4][4] = {};
  for (int s = 0; s < 4; ++s) {              // dk slices of 64
    __syncthreads();
#pragma unroll
    for (int r = 0; r < 16; ++r) {
      int idx = t + 256 * r;
      int row = idx >> 6, col = idx & 63;
      qS[row][col] = q[baseQK + (size_t)row * KDIM + s * 64 + col];
      kS[row][col] = k[baseQK + (size_t)row * KDIM + s * 64 + col];
    }
    __syncthreads();
    for (int d = 0; d < 64; ++d) {
      float a0 = qS[i0][d], a1 = qS[i0 + 1][d], a2 = qS[i0 + 2][d], a3 = qS[i0 + 3][d];
#pragma unroll
      for (int jj = 0; jj < 4; ++jj) {
        float bv = kS[j0 + jj][d];
        acc[0][jj] = fmaf(a0, bv, acc[0][jj]);
        acc[1][jj] = fmaf(a1, bv, acc[1][jj]);
        acc[2][jj] = fmaf(a2, bv, acc[2][jj]);
        acc[3][jj] = fmaf(a3, bv, acc[3][jj]);
      }
    }
  }
  __syncthreads();
#pragma unroll
  for (int ii = 0; ii < 4; ++ii)
#pragma unroll
    for (int jj = 0; jj < 4; ++jj) {
      int i = i0 + ii, j = j0 + jj;
      attnS[i][j] = (i >= j) ? acc[ii][jj] * gpow[i - j] : 0.0f;
    }
  float (*vS)[65] = qS;
  for (int vb = 0; vb < 8; ++vb) {
    __syncthreads();
#pragma unroll
    for (int r = 0; r < 16; ++r) {
      int idx = t + 256 * r;
      int row = idx >> 6, col = idx & 63;
      vS[row][col] = v[baseV + (size_t)row * VDIM + vb * 64 + col];
    }
    __syncthreads();
    float oa[4][4] = {};
    for (int j = 0; j < 64; ++j) {
      float a0 = attnS[i0][j], a1 = attnS[i0 + 1][j], a2 = attnS[i0 + 2][j], a3 = attnS[i0 + 3][j];
#pragma unroll
      for (int jj = 0; jj < 4; ++jj) {
        float bv = vS[j][j0 + jj];
        oa[0][jj] = fmaf(a0, bv, oa[0][jj]);
        oa[1][jj] = fmaf(a1, bv, oa[1][jj]);
        oa[2][jj] = fmaf(a2, bv, oa[2][jj]);
        oa[3][jj] = fmaf(a3, bv, oa[3][jj]);
      }
    }
#pragma unroll
    for (int ii = 0; ii < 4; ++ii)
#pragma unroll
      for (int jj = 0; jj < 4; ++jj)
        o[baseV + (size_t)(i0 + ii) * VDIM + vb * 64 + j0 + jj] = oa[ii][jj];
  }
}

// ---------------- Retention pass 2: inter-chunk scan, dk-split x4 ------------
// Grid (8,4,16) = 512 WGs, 2/CU. Round-5 profile showed this kernel is
// LDS-ISSUE-bound (1536 ds_read_b32 per wave per chunk ~= measured 1085us).
// v2: all LDS traffic as b128. Thread t owns state S[4dk][4dv]:
// dk rows dk0..+3 (dk0=(t&15)*4), dv cols c0..+3 (c0=(t>>4)*4); state loop
// reads 1 float4 of kS + 1 float4 of vS per j. K tile staged to LDS (removes
// 64 global loads from scan path). oa loop blocks d by 4: 8 b128 per 64 FMA.
// Pad 65->68 so rows stay 16B-aligned. Math order per element unchanged.
__global__ __launch_bounds__(256) void retn_inter(const float* __restrict__ q,
                                                  const float* __restrict__ k,
                                                  const float* __restrict__ v,
                                                  float* __restrict__ o) {
  const int vt  = blockIdx.x;
  const int h   = blockIdx.y;
  const int b   = blockIdx.z & 3;
  const int dkg = blockIdx.z >> 2;
  const int t = threadIdx.x;
  __shared__ float gpow[65];
  __shared__ __align__(16) float vS[64][68];
  __shared__ __align__(16) float kS[64][68];
  __shared__ __align__(16) float qS[64][68];
  __shared__ __align__(16) float sS[64][68];
  if (t <= 64) {
    float gamma = 1.0f - exp2f(-5.0f - (float)h);
    gpow[t] = powf(gamma, (float)t);
  }
  __syncthreads();
  const float gC = gpow[64];
  const size_t baseQ = (size_t)(b * T_SEQ) * KDIM + h * HK + dkg * 64;
  const size_t baseV = (size_t)(b * T_SEQ) * VDIM + h * HV + vt * 64;
  const int dk0 = (t & 15) * 4;   // state rows
  const int c0  = (t >> 4) * 4;   // state cols
  const int i0  = (t >> 4) * 4;   // o-tile rows
  const int v0  = (t & 15) * 4;   // o-tile cols
  float S[4][4] = {};

  for (int n = 0; n < 32; ++n) {
    const int t0 = n * 64;
    __syncthreads();   // prev iteration's readers done
    // stage V, K, Q*crossdec tiles (64x64 each) as float4
#pragma unroll
    for (int r = 0; r < 4; ++r) {
      int idx = t + 256 * r;            // 1024 float4 slots = 64 rows x 16
      int row = idx >> 4, c4 = (idx & 15) * 4;
      float4 vv = *(const float4*)&v[baseV + (size_t)(t0 + row) * VDIM + c4];
      *(float4*)&vS[row][c4] = vv;
      float4 kv = *(const float4*)&k[baseQ + (size_t)(t0 + row) * KDIM + c4];
      *(float4*)&kS[row][c4] = kv;
      float4 qv = *(const float4*)&q[baseQ + (size_t)(t0 + row) * KDIM + c4];
      float gp = gpow[row + 1];
      qv.x *= gp; qv.y *= gp; qv.z *= gp; qv.w *= gp;
      *(float4*)&qS[row][c4] = qv;
    }
    // publish S (4 b128 writes, all-distinct float4s)
#pragma unroll
    for (int ii = 0; ii < 4; ++ii)
      *(float4*)&sS[dk0 + ii][c0] = make_float4(S[ii][0], S[ii][1], S[ii][2], S[ii][3]);
    __syncthreads();
    // o_inter tile: oa += qS(64x64) @ sS(64x64), d blocked by 4
    float oa[4][4] = {};
    for (int d = 0; d < 64; d += 4) {
      float a_[4][4], s_[4][4];
#pragma unroll
      for (int ii = 0; ii < 4; ++ii)
        *(float4*)&a_[ii][0] = *(const float4*)&qS[i0 + ii][d];
#pragma unroll
      for (int dd = 0; dd < 4; ++dd)
        *(float4*)&s_[dd][0] = *(const float4*)&sS[d + dd][v0];
#pragma unroll
      for (int dd = 0; dd < 4; ++dd)
#pragma unroll
        for (int ii = 0; ii < 4; ++ii)
#pragma unroll
          for (int jj = 0; jj < 4; ++jj)
            oa[ii][jj] = fmaf(a_[ii][dd], s_[dd][jj], oa[ii][jj]);
    }
#pragma unroll
    for (int ii = 0; ii < 4; ++ii) {
      size_t addr = baseV + (size_t)(t0 + i0 + ii) * VDIM + v0;
#pragma unroll
      for (int jj = 0; jj < 4; ++jj)
        atomicAdd(&o[addr + jj], oa[ii][jj]);
    }
    // state update: S[dk][c] = gC*S + sum_j (kS[j][dk]*gpow[63-j]) * vS[j][c]
#pragma unroll
    for (int ii = 0; ii < 4; ++ii)
#pragma unroll
      for (int c = 0; c < 4; ++c) S[ii][c] *= gC;
    for (int j = 0; j < 64; ++j) {
      float kdec = gpow[63 - j];
      float kv[4], vv[4];
      *(float4*)&kv[0] = *(const float4*)&kS[j][dk0];
      *(float4*)&vv[0] = *(const float4*)&vS[j][c0];
#pragma unroll
      for (int ii = 0; ii < 4; ++ii) {
        float kk_ = kv[ii] * kdec;
#pragma unroll
        for (int c = 0; c < 4; ++c)
          S[ii][c] = fmaf(kk_, vv[c], S[ii][c]);
      }
    }
  }
}

// ---------------- RMS group-norm over HEAD_V + SiLU(g) gate (in-place) -------
__global__ __launch_bounds__(256) void norm_gate(float* __restrict__ o,
                                                 const float* __restrict__ g,
                                                 const float* __restrict__ gnw) {
  const int row = blockIdx.x;
  const size_t base = (size_t)row * 512;
  const int t = threadIdx.x;
  float x0 = o[base + t], x1 = o[base + t + 256];
  float ss = x0 * x0 + x1 * x1;
#pragma unroll
  for (int off = 32; off > 0; off >>= 1) ss += __shfl_down(ss, off, 64);
  __shared__ float wsum[4];
  if ((t & 63) == 0) wsum[t >> 6] = ss;
  __syncthreads();
  float tot = wsum[0] + wsum[1] + wsum[2] + wsum[3];
  float scale = rsqrtf(tot * (1.0f / 512.0f) + 1e-5f);
  float g0 = g[base + t], g1 = g[base + t + 256];
  o[base + t]       = x0 * scale * gnw[t]       * (g0 / (1.0f + expf(-g0)));
  o[base + t + 256] = x1 * scale * gnw[t + 256] * (g1 / (1.0f + expf(-g1)));
}

extern "C" void kernel_launch(void* const* d_in, const int* in_sizes, int n_in,
                              void* d_out, int out_size, void* d_ws, size_t ws_size,
                              hipStream_t stream) {
  const float* x   = (const float*)d_in[0];
  const float* Wq  = (const float*)d_in[1];
  const float* Wk  = (const float*)d_in[2];
  const float* Wv  = (const float*)d_in[3];
  const float* Wg  = (const float*)d_in[4];
  const float* Wo  = (const float*)d_in[5];
  const float* gnw = (const float*)d_in[6];
  float* out = (float*)d_out;

  // workspace = 256 MiB exactly:
  // [q 32][k 32][v 64][o 64][x-splits 32][W-splits 32]
  // o-splits (64) alias dead v; g (64) aliases dead q+k.
  const size_t M8 = (size_t)8192;
  float* q  = (float*)d_ws;
  float* kk = q  + M8 * 1024;
  float* v  = kk + M8 * 1024;
  float* o  = v  + M8 * 2048;
  unsigned short* xh  = (unsigned short*)(o + M8 * 2048);
  unsigned short* xl  = xh  + M8 * 1024;
  unsigned short* wqh = xl  + M8 * 1024;
  unsigned short* wql = wqh + (size_t)1024 * 1024;
  unsigned short* wkh = wql + (size_t)1024 * 1024;
  unsigned short* wkl = wkh + (size_t)1024 * 1024;
  unsigned short* wvh = wkl + (size_t)1024 * 1024;
  unsigned short* wvl = wvh + (size_t)2048 * 1024;
  unsigned short* wgh = wvl + (size_t)2048 * 1024;
  unsigned short* wgl = wgh + (size_t)2048 * 1024;
  unsigned short* woh = wgl + (size_t)2048 * 1024;
  unsigned short* wol = woh + (size_t)2048 * 1024;
  unsigned short* oh  = (unsigned short*)v;
  unsigned short* ol  = oh + M8 * 2048;
  float* g = q;

  dim3 blk(256);
  cast_split<<<dim3(8192), blk, 0, stream>>>(x,  xh,  xl,  2097152);
  cast_split<<<dim3(1024), blk, 0, stream>>>(Wq, wqh, wql, 262144);
  cast_split<<<dim3(1024), blk, 0, stream>>>(Wk, wkh, wkl, 262144);
  cast_split<<<dim3(2048), blk, 0, stream>>>(Wv, wvh, wvl, 524288);
  cast_split<<<dim3(2048), blk, 0, stream>>>(Wg, wgh, wgl, 524288);
  cast_split<<<dim3(2048), blk, 0, stream>>>(Wo, woh, wol, 524288);

  gemm_bf16s<<<dim3(8, 64),  blk, 0, stream>>>(xh, xl, wqh, wql, q,  8192, 1024, 1024);
  gemm_bf16s<<<dim3(8, 64),  blk, 0, stream>>>(xh, xl, wkh, wkl, kk, 8192, 1024, 1024);
  gemm_bf16s<<<dim3(16, 64), blk, 0, stream>>>(xh, xl, wvh, wvl, v,  8192, 2048, 1024);
  rope_kernel<<<dim3(16384), blk, 0, stream>>>(q, kk);
  retn_intra<<<dim3(32, 4, 4),  blk, 0, stream>>>(q, kk, v, o);
  retn_inter<<<dim3(8, 4, 16),  blk, 0, stream>>>(q, kk, v, o);
  gemm_bf16s<<<dim3(16, 64), blk, 0, stream>>>(xh, xl, wgh, wgl, g, 8192, 2048, 1024);
  norm_gate<<<dim3(32768), blk, 0, stream>>>(o, g, gnw);
  cast_split<<<dim3(16384), blk, 0, stream>>>(o, oh, ol, 4194304);
  gemm_bf16s<<<dim3(8, 64),  blk, 0, stream>>>(oh, ol, woh, wol, out, 8192, 1024, 2048);
}